// Round 18
// baseline (418.775 us; speedup 1.0000x reference)
//
#include <hip/hip_runtime.h>
#include <math.h>

#define TOKENS 4096
#define BATCH 64

typedef __attribute__((ext_vector_type(8))) short bf16x8;
typedef __attribute__((ext_vector_type(4))) float f32x4;
union U4B { uint4 u; bf16x8 b; };
union U2x2B { uint2 u[2]; bf16x8 b; };

__device__ __forceinline__ float wsum(float v) {
#pragma unroll
  for (int m = 32; m >= 1; m >>= 1) v += __shfl_xor(v, m);
  return v;
}
__device__ __forceinline__ unsigned short f2bf(float f) {
  unsigned u = __float_as_uint(f);
  u += 0x7fffu + ((u >> 16) & 1u);
  return (unsigned short)(u >> 16);
}
__device__ __forceinline__ float bflo(unsigned p) { return __uint_as_float(p << 16); }
__device__ __forceinline__ float bfhi(unsigned p) { return __uint_as_float(p & 0xffff0000u); }
__device__ __forceinline__ float sigmf(float x) { return 1.f / (1.f + expf(-x)); }

// ================= K_PRE: LN->x  |  weight transposes ==========
__global__ __launch_bounds__(256) void k_pre(
    const float* __restrict__ in, const float* __restrict__ lin_g,
    const float* __restrict__ lin_b, unsigned* __restrict__ x,
    const float* __restrict__ Wq, const float* __restrict__ Wv,
    const float* __restrict__ Wih, const float* __restrict__ Whh,
    const float* __restrict__ W1, const float* __restrict__ W2,
    float* __restrict__ WqT, float* __restrict__ WvT, float* __restrict__ WihT,
    float* __restrict__ WhhT, float* __restrict__ W1T, float* __restrict__ W2T) {
  int bid = blockIdx.x, tid = threadIdx.x;
  if (bid < 65536) {
    int row = bid * 4 + (tid >> 6);
    int lane = tid & 63;
    const float* p = in + (size_t)row * 256 + lane * 4;
    float4 v = *(const float4*)p;
    float s  = wsum(v.x + v.y + v.z + v.w);
    float sq = wsum(v.x * v.x + v.y * v.y + v.z * v.z + v.w * v.w);
    float mu = s * (1.f / 256.f);
    float var = sq * (1.f / 256.f) - mu * mu;
    float rs = rsqrtf(var + 1e-5f);
    float4 gg = *(const float4*)(lin_g + lane * 4);
    float4 bb = *(const float4*)(lin_b + lane * 4);
    float y0 = (v.x - mu) * rs * gg.x + bb.x;
    float y1 = (v.y - mu) * rs * gg.y + bb.y;
    float y2 = (v.z - mu) * rs * gg.z + bb.z;
    float y3 = (v.w - mu) * rs * gg.w + bb.w;
    uint2 o;
    o.x = (unsigned)f2bf(y0) | ((unsigned)f2bf(y1) << 16);
    o.y = (unsigned)f2bf(y2) | ((unsigned)f2bf(y3) << 16);
    *(uint2*)(x + (size_t)row * 128 + lane * 2) = o;
    return;
  }
  {
    __shared__ float t[32][33];
    int t2 = bid - 65536;
    const float* S; float* D; int R; int tile;
    if (t2 < 64)       { S = Wq;  D = WqT;  R = 256; tile = t2; }
    else if (t2 < 128) { S = Wv;  D = WvT;  R = 256; tile = t2 - 64; }
    else if (t2 < 192) { S = W1;  D = W1T;  R = 256; tile = t2 - 128; }
    else if (t2 < 256) { S = W2;  D = W2T;  R = 256; tile = t2 - 192; }
    else if (t2 < 448) { S = Wih; D = WihT; R = 768; tile = t2 - 256; }
    else               { S = Whh; D = WhhT; R = 768; tile = t2 - 448; }
    int rt = R >> 5;
    int r0 = (tile % rt) * 32, c0 = (tile / rt) * 32;
    int ci = tid & 31, r8 = tid >> 5;
#pragma unroll
    for (int k = 0; k < 4; ++k) {
      int r = r8 + k * 8;
      t[r][ci] = S[(size_t)(r0 + r) * 256 + c0 + ci];
    }
    __syncthreads();
#pragma unroll
    for (int k = 0; k < 4; ++k) {
      int r = r8 + k * 8;
      D[(size_t)(c0 + r) * R + r0 + ci] = t[ci][r];
    }
  }
}

// ========== K_QW0: slot init + first-iteration qw (uses WqT) ==========
__global__ __launch_bounds__(256) void k_qw0(
    const float* __restrict__ smu, const float* __restrict__ slsig,
    const float* __restrict__ noise, const float* __restrict__ lsl_g,
    const float* __restrict__ lsl_b, const float* __restrict__ WqT,
    const float* __restrict__ Wk, float* __restrict__ slots,
    unsigned* __restrict__ qwb) {
  __shared__ float ln[256];
  __shared__ float q[256];
  __shared__ float red[8];
  int n = blockIdx.x, s = blockIdx.y, tid = threadIdx.x;
  int sd = s * 256 + tid;
  float v = smu[sd] + expf(slsig[sd]) * noise[(size_t)n * 2048 + sd];
  slots[(size_t)n * 2048 + sd] = v;
  float ps = wsum(v), pq = wsum(v * v);
  if ((tid & 63) == 0) { red[tid >> 6] = ps; red[4 + (tid >> 6)] = pq; }
  __syncthreads();
  float sum = red[0] + red[1] + red[2] + red[3];
  float sqq = red[4] + red[5] + red[6] + red[7];
  float mu = sum * (1.f / 256.f);
  float var = sqq * (1.f / 256.f) - mu * mu;
  float rs = rsqrtf(var + 1e-5f);
  ln[tid] = (v - mu) * rs * lsl_g[tid] + lsl_b[tid];
  __syncthreads();
  float a = 0.f;
  for (int d = 0; d < 256; ++d) a += ln[d] * WqT[d * 256 + tid];
  q[tid] = a;
  __syncthreads();
  float c = 0.f;
  for (int e = 0; e < 256; ++e) c += q[e] * Wk[(size_t)e * 256 + tid];
  c *= 0.0625f;
  __syncthreads();
  ln[tid] = c;
  __syncthreads();
  if (tid < 128)
    qwb[((size_t)n * 8 + s) * 128 + tid] =
        (unsigned)f2bf(ln[2 * tid]) | ((unsigned)f2bf(ln[2 * tid + 1]) << 16);
}

// ========== K_ATT4P: 4 chunks/block with register-prefetch double buffer ====
__global__ __launch_bounds__(256) void k_att4p(const unsigned* __restrict__ x,
                                               const unsigned* __restrict__ qwb,
                                               float* __restrict__ stats,
                                               float* __restrict__ axp) {
  __shared__ unsigned xs[64][130];
  __shared__ float lsT[64][8];
  __shared__ float redS[8][4];
  int bx = blockIdx.x, n = blockIdx.y;
  int tid = threadIdx.x, wv = tid >> 6, l = tid & 63;
  int col = l & 15, g = l >> 4;
  int lane32 = tid & 31, g8 = tid >> 5;
  uint4 a[8];
  {
    const unsigned* ap = qwb + ((size_t)n * 8 + (l & 7)) * 128 + g * 4;
#pragma unroll
    for (int kk = 0; kk < 8; ++kk) a[kk] = *(const uint4*)(ap + kk * 16);
  }
  float pv[8] = {0, 0, 0, 0, 0, 0, 0, 0};
  float SS = 0.f;
  int s = tid & 7, tg = tid >> 3;
  const unsigned* base = x + ((size_t)n * 4096 + bx * 256) * 128 + lane32 * 4;
  uint4 st[8];
#pragma unroll
  for (int p = 0; p < 8; ++p)
    st[p] = *(const uint4*)(base + (size_t)(p * 8 + g8) * 128);
#pragma unroll
  for (int p = 0; p < 8; ++p) {
    unsigned* dr = &xs[p * 8 + g8][lane32 * 4];
    *(uint2*)dr = make_uint2(st[p].x, st[p].y);
    *(uint2*)(dr + 2) = make_uint2(st[p].z, st[p].w);
  }
  __syncthreads();
  for (int cc = 0; cc < 4; ++cc) {
    if (cc < 3) {
      const unsigned* src = base + (size_t)(cc + 1) * 64 * 128;
#pragma unroll
      for (int p = 0; p < 8; ++p)
        st[p] = *(const uint4*)(src + (size_t)(p * 8 + g8) * 128);
    }
    {
      int t0 = wv * 16;
      const unsigned* xr = &xs[t0 + col][0];
      f32x4 qacc = {0.f, 0.f, 0.f, 0.f};
#pragma unroll
      for (int kk = 0; kk < 8; ++kk) {
        U4B aa; aa.u = a[kk];
        U2x2B bb;
        bb.u[0] = *(const uint2*)(xr + kk * 16 + g * 4);
        bb.u[1] = *(const uint2*)(xr + kk * 16 + g * 4 + 2);
        qacc = __builtin_amdgcn_mfma_f32_16x16x32_bf16(aa.b, bb.b, qacc, 0, 0, 0);
      }
      if (g < 2) {
#pragma unroll
        for (int r = 0; r < 4; ++r) lsT[t0 + col][g * 4 + r] = qacc[r];
      }
    }
    __syncthreads();
    {
      float e0 = __expf(lsT[tg][s]);
      float e1 = __expf(lsT[tg + 32][s]);
      lsT[tg][s] = e0;
      lsT[tg + 32][s] = e1;
      float S = e0 + e1;
      S += __shfl_xor(S, 8);
      S += __shfl_xor(S, 16);
      S += __shfl_xor(S, 32);
      if (l < 8) redS[s][wv] = S;
    }
    __syncthreads();
    if (tid < 8)
      SS += redS[tid][0] + redS[tid][1] + redS[tid][2] + redS[tid][3];
    {
      int d = tid;
#pragma unroll 8
      for (int t = 0; t < 64; ++t) {
        unsigned pw = xs[t][d >> 1];
        float xv = (d & 1) ? bfhi(pw) : bflo(pw);
        float4 p0 = *(const float4*)&lsT[t][0];
        float4 p1 = *(const float4*)&lsT[t][4];
        pv[0] += p0.x * xv; pv[1] += p0.y * xv;
        pv[2] += p0.z * xv; pv[3] += p0.w * xv;
        pv[4] += p1.x * xv; pv[5] += p1.y * xv;
        pv[6] += p1.z * xv; pv[7] += p1.w * xv;
      }
    }
    __syncthreads();
    if (cc < 3) {
#pragma unroll
      for (int p = 0; p < 8; ++p) {
        unsigned* dr = &xs[p * 8 + g8][lane32 * 4];
        *(uint2*)dr = make_uint2(st[p].x, st[p].y);
        *(uint2*)(dr + 2) = make_uint2(st[p].z, st[p].w);
      }
      __syncthreads();
    }
  }
  if (tid < 8) stats[((size_t)n * 8 + tid) * 16 + bx] = SS;
  {
    float* op = axp + ((size_t)n * 16 + bx) * 2048 + tid;
#pragma unroll
    for (int ss = 0; ss < 8; ++ss) op[ss * 256] = pv[ss];
  }
}

// ========== K_UPDATE6: 2 batches per block (amortize weight L2 traffic) =====
// grid (32, 8), 256 threads: block = (n-pair, slot). Weight reads halve vs
// the (64,8) layout; all GEMV phases keep 2 accumulators.
__global__ __launch_bounds__(256) void k_update6(
    const float* __restrict__ axp, const float* __restrict__ stats,
    const float* __restrict__ slots_in,
    const float* __restrict__ WvT, const float* __restrict__ WihT,
    const float* __restrict__ WhhT, const float* __restrict__ b_ih,
    const float* __restrict__ b_hh, const float* __restrict__ W1T,
    const float* __restrict__ b1, const float* __restrict__ W2T,
    const float* __restrict__ b2, const float* __restrict__ lml_g,
    const float* __restrict__ lml_b, const float* __restrict__ lsl_g,
    const float* __restrict__ lsl_b, const float* __restrict__ WqT,
    const float* __restrict__ Wk, unsigned* __restrict__ qwb, int doQw,
    float* __restrict__ slots_out) {
  __shared__ float ax[2][256];
  __shared__ float sp[2][256];
  __shared__ float upd[2][256];
  __shared__ float sn[2][256];
  __shared__ float lnv[2][256];
  __shared__ float hid[2][256];
  __shared__ float red[16];
  __shared__ float Sinv[2];
  int n0 = blockIdx.x * 2, s = blockIdx.y, tid = threadIdx.x;
  // Sinv for both n (waves 0,1 in parallel)
  {
    int w = tid >> 6, l = tid & 63;
    if (w < 2) {
      float sv = (l < 16) ? stats[((size_t)(n0 + w) * 8 + s) * 16 + l] : 0.f;
      sv = wsum(sv);
      if (l == 0) Sinv[w] = 1.f / (sv * (1.f + 1e-8f));
    }
  }
  // combine 16 chunk partials for both n
  {
    float acc0 = 0.f, acc1 = 0.f;
    const float* p0 = axp + (size_t)n0 * 32768 + s * 256 + tid;
#pragma unroll 8
    for (int c = 0; c < 16; ++c) {
      acc0 += p0[(size_t)c * 2048];
      acc1 += p0[32768 + (size_t)c * 2048];
    }
    sp[0][tid] = slots_in[((size_t)n0 * 8 + s) * 256 + tid];
    sp[1][tid] = slots_in[((size_t)(n0 + 1) * 8 + s) * 256 + tid];
    __syncthreads();
    ax[0][tid] = acc0 * Sinv[0];
    ax[1][tid] = acc1 * Sinv[1];
  }
  __syncthreads();
  // upd = ax @ WvT (weights read once, used for both n)
  {
    float a0 = 0.f, a1 = 0.f;
    for (int d = 0; d < 256; ++d) {
      float w = WvT[d * 256 + tid];
      a0 += ax[0][d] * w;
      a1 += ax[1][d] * w;
    }
    upd[0][tid] = a0;
    upd[1][tid] = a1;
  }
  __syncthreads();
  // fused GRU: thread j computes r,z,n gates for both n
  {
    int j = tid;
    float gr0 = 0.f, gz0 = 0.f, gn0 = 0.f, hr0 = 0.f, hz0 = 0.f, hn0 = 0.f;
    float gr1 = 0.f, gz1 = 0.f, gn1 = 0.f, hr1 = 0.f, hz1 = 0.f, hn1 = 0.f;
    for (int d = 0; d < 256; ++d) {
      float wir = WihT[d * 768 + j];
      float wiz = WihT[d * 768 + j + 256];
      float win = WihT[d * 768 + j + 512];
      float whr = WhhT[d * 768 + j];
      float whz = WhhT[d * 768 + j + 256];
      float whn = WhhT[d * 768 + j + 512];
      float u0 = upd[0][d], s0 = sp[0][d];
      float u1 = upd[1][d], s1 = sp[1][d];
      gr0 += u0 * wir; gz0 += u0 * wiz; gn0 += u0 * win;
      hr0 += s0 * whr; hz0 += s0 * whz; hn0 += s0 * whn;
      gr1 += u1 * wir; gz1 += u1 * wiz; gn1 += u1 * win;
      hr1 += s1 * whr; hz1 += s1 * whz; hn1 += s1 * whn;
    }
    float bir = b_ih[j], biz = b_ih[j + 256], bin = b_ih[j + 512];
    float bhr = b_hh[j], bhz = b_hh[j + 256], bhn = b_hh[j + 512];
    float r0 = sigmf(gr0 + bir + hr0 + bhr);
    float z0 = sigmf(gz0 + biz + hz0 + bhz);
    float h0 = tanhf(gn0 + bin + r0 * (hn0 + bhn));
    sn[0][j] = (1.f - z0) * h0 + z0 * sp[0][j];
    float r1 = sigmf(gr1 + bir + hr1 + bhr);
    float z1 = sigmf(gz1 + biz + hz1 + bhz);
    float h1 = tanhf(gn1 + bin + r1 * (hn1 + bhn));
    sn[1][j] = (1.f - z1) * h1 + z1 * sp[1][j];
  }
  __syncthreads();
  // LN(sn) lml: 128 threads per n (2 elems each)
  {
    int k = tid >> 7, qq = tid & 127;
    float v0 = sn[k][qq], v1 = sn[k][qq + 128];
    float ps = wsum(v0 + v1);
    float pq = wsum(v0 * v0 + v1 * v1);
    int wid = tid >> 6;
    if ((tid & 63) == 0) { red[wid] = ps; red[8 + wid] = pq; }
    __syncthreads();
    float ssum = red[k * 2] + red[k * 2 + 1];
    float sqq  = red[8 + k * 2] + red[8 + k * 2 + 1];
    float mu = ssum * (1.f / 256.f);
    float var = sqq * (1.f / 256.f) - mu * mu;
    float rs = rsqrtf(var + 1e-5f);
    lnv[k][qq]       = (v0 - mu) * rs * lml_g[qq] + lml_b[qq];
    lnv[k][qq + 128] = (v1 - mu) * rs * lml_g[qq + 128] + lml_b[qq + 128];
  }
  __syncthreads();
  // hid = relu(lnv @ W1T + b1)
  {
    float a0 = 0.f, a1 = 0.f;
    for (int d = 0; d < 256; ++d) {
      float w = W1T[d * 256 + tid];
      a0 += lnv[0][d] * w;
      a1 += lnv[1][d] * w;
    }
    float b = b1[tid];
    hid[0][tid] = fmaxf(a0 + b, 0.f);
    hid[1][tid] = fmaxf(a1 + b, 0.f);
  }
  __syncthreads();
  // out = sn + hid @ W2T + b2
  {
    float a0 = 0.f, a1 = 0.f;
    for (int d = 0; d < 256; ++d) {
      float w = W2T[d * 256 + tid];
      a0 += hid[0][d] * w;
      a1 += hid[1][d] * w;
    }
    float b = b2[tid];
    float o0 = sn[0][tid] + a0 + b;
    float o1 = sn[1][tid] + a1 + b;
    slots_out[((size_t)n0 * 8 + s) * 256 + tid] = o0;
    slots_out[((size_t)(n0 + 1) * 8 + s) * 256 + tid] = o1;
    ax[0][tid] = o0;
    ax[1][tid] = o1;
  }
  if (!doQw) return;
  __syncthreads();
  // LN(new slots) lsl -> sp
  {
    int k = tid >> 7, qq = tid & 127;
    float v0 = ax[k][qq], v1 = ax[k][qq + 128];
    float ps = wsum(v0 + v1);
    float pq = wsum(v0 * v0 + v1 * v1);
    int wid = tid >> 6;
    if ((tid & 63) == 0) { red[wid] = ps; red[8 + wid] = pq; }
    __syncthreads();
    float ssum = red[k * 2] + red[k * 2 + 1];
    float sqq  = red[8 + k * 2] + red[8 + k * 2 + 1];
    float mu = ssum * (1.f / 256.f);
    float var = sqq * (1.f / 256.f) - mu * mu;
    float rs = rsqrtf(var + 1e-5f);
    sp[k][qq]       = (v0 - mu) * rs * lsl_g[qq] + lsl_b[qq];
    sp[k][qq + 128] = (v1 - mu) * rs * lsl_g[qq + 128] + lsl_b[qq + 128];
  }
  __syncthreads();
  // qv = LN @ WqT
  {
    float a0 = 0.f, a1 = 0.f;
    for (int d = 0; d < 256; ++d) {
      float w = WqT[d * 256 + tid];
      a0 += sp[0][d] * w;
      a1 += sp[1][d] * w;
    }
    upd[0][tid] = a0;
    upd[1][tid] = a1;
  }
  __syncthreads();
  // qw = qv @ Wk * scale
  {
    float c0 = 0.f, c1 = 0.f;
    for (int ee = 0; ee < 256; ++ee) {
      float w = Wk[(size_t)ee * 256 + tid];
      c0 += upd[0][ee] * w;
      c1 += upd[1][ee] * w;
    }
    hid[0][tid] = c0 * 0.0625f;
    hid[1][tid] = c1 * 0.0625f;
  }
  __syncthreads();
  if (tid < 128) {
    qwb[((size_t)n0 * 8 + s) * 128 + tid] =
        (unsigned)f2bf(hid[0][2 * tid]) | ((unsigned)f2bf(hid[0][2 * tid + 1]) << 16);
    qwb[((size_t)(n0 + 1) * 8 + s) * 128 + tid] =
        (unsigned)f2bf(hid[1][2 * tid]) | ((unsigned)f2bf(hid[1][2 * tid + 1]) << 16);
  }
}

extern "C" void kernel_launch(void* const* d_in, const int* in_sizes, int n_in,
                              void* d_out, int out_size, void* d_ws, size_t ws_size,
                              hipStream_t stream) {
  (void)in_sizes; (void)n_in; (void)out_size; (void)ws_size;
  const float* inputs = (const float*)d_in[0];
  const float* noise  = (const float*)d_in[1];
  const float* smu    = (const float*)d_in[2];
  const float* slsig  = (const float*)d_in[3];
  const float* Wq     = (const float*)d_in[4];
  const float* Wk     = (const float*)d_in[5];
  const float* Wv     = (const float*)d_in[6];
  const float* W_ih   = (const float*)d_in[7];
  const float* W_hh   = (const float*)d_in[8];
  const float* b_ih   = (const float*)d_in[9];
  const float* b_hh   = (const float*)d_in[10];
  const float* W1     = (const float*)d_in[11];
  const float* b1     = (const float*)d_in[12];
  const float* W2     = (const float*)d_in[13];
  const float* b2     = (const float*)d_in[14];
  const float* lin_g  = (const float*)d_in[15];
  const float* lin_b  = (const float*)d_in[16];
  const float* lsl_g  = (const float*)d_in[17];
  const float* lsl_b  = (const float*)d_in[18];
  const float* lml_g  = (const float*)d_in[19];
  const float* lml_b  = (const float*)d_in[20];
  float* out = (float*)d_out;
  char* ws = (char*)d_ws;
  unsigned* x    = (unsigned*)(ws + 0);            // 134217728
  unsigned* qwb  = (unsigned*)(ws + 134217728);    // 262144
  float* stats   = (float*)(ws + 134479872);       // 32768
  float* axp     = (float*)(ws + 134610944);       // 8388608
  float* WqT     = (float*)(ws + 168165376);       // 262144
  float* WvT     = (float*)(ws + 168427520);       // 262144
  float* WihT    = (float*)(ws + 168689664);       // 786432
  float* WhhT    = (float*)(ws + 169476096);       // 786432
  float* W1T     = (float*)(ws + 170262528);       // 262144
  float* W2T     = (float*)(ws + 170524672);       // 262144

  k_pre<<<dim3(66176), 256, 0, stream>>>(inputs, lin_g, lin_b, x,
                                         Wq, Wv, W_ih, W_hh, W1, W2,
                                         WqT, WvT, WihT, WhhT, W1T, W2T);
  k_qw0<<<dim3(BATCH, 8), 256, 0, stream>>>(smu, slsig, noise, lsl_g, lsl_b,
                                            WqT, Wk, out, qwb);
  for (int it = 0; it < 3; ++it) {
    k_att4p<<<dim3(16, BATCH), 256, 0, stream>>>(x, qwb, stats, axp);
    k_update6<<<dim3(32, 8), 256, 0, stream>>>(
        axp, stats, out, WvT, WihT, WhhT, b_ih, b_hh, W1T, b1, W2T, b2,
        lml_g, lml_b, lsl_g, lsl_b, WqT, Wk, qwb, (it < 2) ? 1 : 0, out);
  }
}

// Round 19
// 380.499 us; speedup vs baseline: 1.1006x; 1.1006x over previous
//
#include <hip/hip_runtime.h>
#include <math.h>

#define TOKENS 4096
#define BATCH 64

typedef __attribute__((ext_vector_type(8))) short bf16x8;
typedef __attribute__((ext_vector_type(4))) float f32x4;
union U4B { uint4 u; bf16x8 b; };
union U2x2B { uint2 u[2]; bf16x8 b; };

__device__ __forceinline__ float wsum(float v) {
#pragma unroll
  for (int m = 32; m >= 1; m >>= 1) v += __shfl_xor(v, m);
  return v;
}
__device__ __forceinline__ unsigned short f2bf(float f) {
  unsigned u = __float_as_uint(f);
  u += 0x7fffu + ((u >> 16) & 1u);
  return (unsigned short)(u >> 16);
}
__device__ __forceinline__ float bflo(unsigned p) { return __uint_as_float(p << 16); }
__device__ __forceinline__ float bfhi(unsigned p) { return __uint_as_float(p & 0xffff0000u); }
__device__ __forceinline__ float sigmf(float x) { return 1.f / (1.f + expf(-x)); }

// ================= K_PRE: LN->x  |  weight transposes ==========
__global__ __launch_bounds__(256) void k_pre(
    const float* __restrict__ in, const float* __restrict__ lin_g,
    const float* __restrict__ lin_b, unsigned* __restrict__ x,
    const float* __restrict__ Wq, const float* __restrict__ Wv,
    const float* __restrict__ Wih, const float* __restrict__ Whh,
    const float* __restrict__ W1, const float* __restrict__ W2,
    float* __restrict__ WqT, float* __restrict__ WvT, float* __restrict__ WihT,
    float* __restrict__ WhhT, float* __restrict__ W1T, float* __restrict__ W2T) {
  int bid = blockIdx.x, tid = threadIdx.x;
  if (bid < 65536) {
    int row = bid * 4 + (tid >> 6);
    int lane = tid & 63;
    const float* p = in + (size_t)row * 256 + lane * 4;
    float4 v = *(const float4*)p;
    float s  = wsum(v.x + v.y + v.z + v.w);
    float sq = wsum(v.x * v.x + v.y * v.y + v.z * v.z + v.w * v.w);
    float mu = s * (1.f / 256.f);
    float var = sq * (1.f / 256.f) - mu * mu;
    float rs = rsqrtf(var + 1e-5f);
    float4 gg = *(const float4*)(lin_g + lane * 4);
    float4 bb = *(const float4*)(lin_b + lane * 4);
    float y0 = (v.x - mu) * rs * gg.x + bb.x;
    float y1 = (v.y - mu) * rs * gg.y + bb.y;
    float y2 = (v.z - mu) * rs * gg.z + bb.z;
    float y3 = (v.w - mu) * rs * gg.w + bb.w;
    uint2 o;
    o.x = (unsigned)f2bf(y0) | ((unsigned)f2bf(y1) << 16);
    o.y = (unsigned)f2bf(y2) | ((unsigned)f2bf(y3) << 16);
    *(uint2*)(x + (size_t)row * 128 + lane * 2) = o;
    return;
  }
  {
    __shared__ float t[32][33];
    int t2 = bid - 65536;
    const float* S; float* D; int R; int tile;
    if (t2 < 64)       { S = Wq;  D = WqT;  R = 256; tile = t2; }
    else if (t2 < 128) { S = Wv;  D = WvT;  R = 256; tile = t2 - 64; }
    else if (t2 < 192) { S = W1;  D = W1T;  R = 256; tile = t2 - 128; }
    else if (t2 < 256) { S = W2;  D = W2T;  R = 256; tile = t2 - 192; }
    else if (t2 < 448) { S = Wih; D = WihT; R = 768; tile = t2 - 256; }
    else               { S = Whh; D = WhhT; R = 768; tile = t2 - 448; }
    int rt = R >> 5;
    int r0 = (tile % rt) * 32, c0 = (tile / rt) * 32;
    int ci = tid & 31, r8 = tid >> 5;
#pragma unroll
    for (int k = 0; k < 4; ++k) {
      int r = r8 + k * 8;
      t[r][ci] = S[(size_t)(r0 + r) * 256 + c0 + ci];
    }
    __syncthreads();
#pragma unroll
    for (int k = 0; k < 4; ++k) {
      int r = r8 + k * 8;
      D[(size_t)(c0 + r) * R + r0 + ci] = t[ci][r];
    }
  }
}

// ========== K_QW0: slot init + first-iteration qw (uses WqT) ==========
__global__ __launch_bounds__(256) void k_qw0(
    const float* __restrict__ smu, const float* __restrict__ slsig,
    const float* __restrict__ noise, const float* __restrict__ lsl_g,
    const float* __restrict__ lsl_b, const float* __restrict__ WqT,
    const float* __restrict__ Wk, float* __restrict__ slots,
    unsigned* __restrict__ qwb) {
  __shared__ float ln[256];
  __shared__ float q[256];
  __shared__ float red[8];
  int n = blockIdx.x, s = blockIdx.y, tid = threadIdx.x;
  int sd = s * 256 + tid;
  float v = smu[sd] + expf(slsig[sd]) * noise[(size_t)n * 2048 + sd];
  slots[(size_t)n * 2048 + sd] = v;
  float ps = wsum(v), pq = wsum(v * v);
  if ((tid & 63) == 0) { red[tid >> 6] = ps; red[4 + (tid >> 6)] = pq; }
  __syncthreads();
  float sum = red[0] + red[1] + red[2] + red[3];
  float sqq = red[4] + red[5] + red[6] + red[7];
  float mu = sum * (1.f / 256.f);
  float var = sqq * (1.f / 256.f) - mu * mu;
  float rs = rsqrtf(var + 1e-5f);
  ln[tid] = (v - mu) * rs * lsl_g[tid] + lsl_b[tid];
  __syncthreads();
  float a = 0.f;
  for (int d = 0; d < 256; ++d) a += ln[d] * WqT[d * 256 + tid];
  q[tid] = a;
  __syncthreads();
  float c = 0.f;
  for (int e = 0; e < 256; ++e) c += q[e] * Wk[(size_t)e * 256 + tid];
  c *= 0.0625f;
  __syncthreads();
  ln[tid] = c;
  __syncthreads();
  if (tid < 128)
    qwb[((size_t)n * 8 + s) * 128 + tid] =
        (unsigned)f2bf(ln[2 * tid]) | ((unsigned)f2bf(ln[2 * tid + 1]) << 16);
}

// ========== K_ATT4P: 4 chunks/block, register-prefetch, XCD-swizzled ========
// grid 1024 flat. Swizzle: XCD k owns n in [8k, 8k+8) so each XCD's L2
// caches only 16MB of x and same-n blocks share their 2MB slice.
__global__ __launch_bounds__(256) void k_att4p(const unsigned* __restrict__ x,
                                               const unsigned* __restrict__ qwb,
                                               float* __restrict__ stats,
                                               float* __restrict__ axp) {
  __shared__ unsigned xs[64][130];
  __shared__ float lsT[64][8];
  __shared__ float redS[8][4];
  // XCD-aware swizzle of the flat block id (1024 = 8 XCDs x 128)
  int lin = blockIdx.x;
  int sw = (lin & 7) * 128 + (lin >> 3);
  int bx = sw & 15, n = sw >> 4;
  int tid = threadIdx.x, wv = tid >> 6, l = tid & 63;
  int col = l & 15, g = l >> 4;
  int lane32 = tid & 31, g8 = tid >> 5;
  uint4 a[8];
  {
    const unsigned* ap = qwb + ((size_t)n * 8 + (l & 7)) * 128 + g * 4;
#pragma unroll
    for (int kk = 0; kk < 8; ++kk) a[kk] = *(const uint4*)(ap + kk * 16);
  }
  float pv[8] = {0, 0, 0, 0, 0, 0, 0, 0};
  float SS = 0.f;
  int s = tid & 7, tg = tid >> 3;
  const unsigned* base = x + ((size_t)n * 4096 + bx * 256) * 128 + lane32 * 4;
  uint4 st[8];
#pragma unroll
  for (int p = 0; p < 8; ++p)
    st[p] = *(const uint4*)(base + (size_t)(p * 8 + g8) * 128);
#pragma unroll
  for (int p = 0; p < 8; ++p) {
    unsigned* dr = &xs[p * 8 + g8][lane32 * 4];
    *(uint2*)dr = make_uint2(st[p].x, st[p].y);
    *(uint2*)(dr + 2) = make_uint2(st[p].z, st[p].w);
  }
  __syncthreads();
  for (int cc = 0; cc < 4; ++cc) {
    if (cc < 3) {
      const unsigned* src = base + (size_t)(cc + 1) * 64 * 128;
#pragma unroll
      for (int p = 0; p < 8; ++p)
        st[p] = *(const uint4*)(src + (size_t)(p * 8 + g8) * 128);
    }
    {
      int t0 = wv * 16;
      const unsigned* xr = &xs[t0 + col][0];
      f32x4 qacc = {0.f, 0.f, 0.f, 0.f};
#pragma unroll
      for (int kk = 0; kk < 8; ++kk) {
        U4B aa; aa.u = a[kk];
        U2x2B bb;
        bb.u[0] = *(const uint2*)(xr + kk * 16 + g * 4);
        bb.u[1] = *(const uint2*)(xr + kk * 16 + g * 4 + 2);
        qacc = __builtin_amdgcn_mfma_f32_16x16x32_bf16(aa.b, bb.b, qacc, 0, 0, 0);
      }
      if (g < 2) {
#pragma unroll
        for (int r = 0; r < 4; ++r) lsT[t0 + col][g * 4 + r] = qacc[r];
      }
    }
    __syncthreads();
    {
      float e0 = __expf(lsT[tg][s]);
      float e1 = __expf(lsT[tg + 32][s]);
      lsT[tg][s] = e0;
      lsT[tg + 32][s] = e1;
      float S = e0 + e1;
      S += __shfl_xor(S, 8);
      S += __shfl_xor(S, 16);
      S += __shfl_xor(S, 32);
      if (l < 8) redS[s][wv] = S;
    }
    __syncthreads();
    if (tid < 8)
      SS += redS[tid][0] + redS[tid][1] + redS[tid][2] + redS[tid][3];
    {
      int d = tid;
#pragma unroll 8
      for (int t = 0; t < 64; ++t) {
        unsigned pw = xs[t][d >> 1];
        float xv = (d & 1) ? bfhi(pw) : bflo(pw);
        float4 p0 = *(const float4*)&lsT[t][0];
        float4 p1 = *(const float4*)&lsT[t][4];
        pv[0] += p0.x * xv; pv[1] += p0.y * xv;
        pv[2] += p0.z * xv; pv[3] += p0.w * xv;
        pv[4] += p1.x * xv; pv[5] += p1.y * xv;
        pv[6] += p1.z * xv; pv[7] += p1.w * xv;
      }
    }
    __syncthreads();
    if (cc < 3) {
#pragma unroll
      for (int p = 0; p < 8; ++p) {
        unsigned* dr = &xs[p * 8 + g8][lane32 * 4];
        *(uint2*)dr = make_uint2(st[p].x, st[p].y);
        *(uint2*)(dr + 2) = make_uint2(st[p].z, st[p].w);
      }
      __syncthreads();
    }
  }
  if (tid < 8) stats[((size_t)n * 8 + tid) * 16 + bx] = SS;
  {
    float* op = axp + ((size_t)n * 16 + bx) * 2048 + tid;
#pragma unroll
    for (int ss = 0; ss < 8; ++ss) op[ss * 256] = pv[ss];
  }
}

// ========== K_UPDATE5: one (n,slot) per block; combine, Wv, GRU, LN, MLP ====
// grid (64, 8), 256 threads.
__global__ __launch_bounds__(256) void k_update5(
    const float* __restrict__ axp, const float* __restrict__ stats,
    const float* __restrict__ slots_in,
    const float* __restrict__ WvT, const float* __restrict__ WihT,
    const float* __restrict__ WhhT, const float* __restrict__ b_ih,
    const float* __restrict__ b_hh, const float* __restrict__ W1T,
    const float* __restrict__ b1, const float* __restrict__ W2T,
    const float* __restrict__ b2, const float* __restrict__ lml_g,
    const float* __restrict__ lml_b, const float* __restrict__ lsl_g,
    const float* __restrict__ lsl_b, const float* __restrict__ WqT,
    const float* __restrict__ Wk, unsigned* __restrict__ qwb, int doQw,
    float* __restrict__ slots_out) {
  __shared__ float ax[256];
  __shared__ float sp[256];
  __shared__ float upd[256];
  __shared__ float sn[256];
  __shared__ float lnv[256];
  __shared__ float hid[256];
  __shared__ float red[8];
  int n = blockIdx.x, s = blockIdx.y, tid = threadIdx.x;
  {
    float sv = 0.f;
    if (tid < 16) sv = stats[((size_t)n * 8 + s) * 16 + tid];
    if (tid < 64) {
      sv = wsum(sv);
      if (tid == 0) red[0] = 1.f / (sv * (1.f + 1e-8f));
    }
  }
  {
    const float* pp = axp + (size_t)n * 32768 + s * 256 + tid;
    float acc = 0.f;
#pragma unroll 8
    for (int c = 0; c < 16; ++c) acc += pp[(size_t)c * 2048];
    sp[tid] = slots_in[((size_t)n * 8 + s) * 256 + tid];
    __syncthreads();
    ax[tid] = acc * red[0];
  }
  __syncthreads();
  {
    float a0 = 0.f;
    for (int d = 0; d < 256; ++d) a0 += ax[d] * WvT[d * 256 + tid];
    upd[tid] = a0;
  }
  __syncthreads();
  {
    int j = tid;
    float gr = 0.f, gz = 0.f, gn = 0.f, hr = 0.f, hz = 0.f, hn = 0.f;
    for (int d = 0; d < 256; ++d) {
      float u = upd[d], s_ = sp[d];
      gr += u * WihT[d * 768 + j];
      gz += u * WihT[d * 768 + j + 256];
      gn += u * WihT[d * 768 + j + 512];
      hr += s_ * WhhT[d * 768 + j];
      hz += s_ * WhhT[d * 768 + j + 256];
      hn += s_ * WhhT[d * 768 + j + 512];
    }
    float r = sigmf(gr + b_ih[j] + hr + b_hh[j]);
    float z = sigmf(gz + b_ih[j + 256] + hz + b_hh[j + 256]);
    float hh = tanhf(gn + b_ih[j + 512] + r * (hn + b_hh[j + 512]));
    sn[j] = (1.f - z) * hh + z * sp[j];
  }
  __syncthreads();
  {
    float v = sn[tid];
    float ps = wsum(v), pq = wsum(v * v);
    if ((tid & 63) == 0) { red[tid >> 6] = ps; red[4 + (tid >> 6)] = pq; }
    __syncthreads();
    float sum = red[0] + red[1] + red[2] + red[3];
    float sqq = red[4] + red[5] + red[6] + red[7];
    float mu = sum * (1.f / 256.f);
    float var = sqq * (1.f / 256.f) - mu * mu;
    float rs = rsqrtf(var + 1e-5f);
    lnv[tid] = (v - mu) * rs * lml_g[tid] + lml_b[tid];
  }
  __syncthreads();
  {
    float a0 = 0.f;
    for (int d = 0; d < 256; ++d) a0 += lnv[d] * W1T[d * 256 + tid];
    hid[tid] = fmaxf(a0 + b1[tid], 0.f);
  }
  __syncthreads();
  {
    float a0 = 0.f;
    for (int d = 0; d < 256; ++d) a0 += hid[d] * W2T[d * 256 + tid];
    float o = sn[tid] + a0 + b2[tid];
    slots_out[((size_t)n * 8 + s) * 256 + tid] = o;
    ax[tid] = o;
  }
  if (!doQw) return;
  __syncthreads();
  {
    float v = ax[tid];
    float ps = wsum(v), pq = wsum(v * v);
    if ((tid & 63) == 0) { red[tid >> 6] = ps; red[4 + (tid >> 6)] = pq; }
    __syncthreads();
    float sum = red[0] + red[1] + red[2] + red[3];
    float sqq = red[4] + red[5] + red[6] + red[7];
    float mu = sum * (1.f / 256.f);
    float var = sqq * (1.f / 256.f) - mu * mu;
    float rs = rsqrtf(var + 1e-5f);
    sp[tid] = (v - mu) * rs * lsl_g[tid] + lsl_b[tid];
  }
  __syncthreads();
  {
    float a0 = 0.f;
    for (int d = 0; d < 256; ++d) a0 += sp[d] * WqT[d * 256 + tid];
    upd[tid] = a0;
  }
  __syncthreads();
  {
    float c0 = 0.f;
    for (int ee = 0; ee < 256; ++ee) c0 += upd[ee] * Wk[(size_t)ee * 256 + tid];
    hid[tid] = c0 * 0.0625f;
  }
  __syncthreads();
  if (tid < 128)
    qwb[((size_t)n * 8 + s) * 128 + tid] =
        (unsigned)f2bf(hid[2 * tid]) | ((unsigned)f2bf(hid[2 * tid + 1]) << 16);
}

extern "C" void kernel_launch(void* const* d_in, const int* in_sizes, int n_in,
                              void* d_out, int out_size, void* d_ws, size_t ws_size,
                              hipStream_t stream) {
  (void)in_sizes; (void)n_in; (void)out_size; (void)ws_size;
  const float* inputs = (const float*)d_in[0];
  const float* noise  = (const float*)d_in[1];
  const float* smu    = (const float*)d_in[2];
  const float* slsig  = (const float*)d_in[3];
  const float* Wq     = (const float*)d_in[4];
  const float* Wk     = (const float*)d_in[5];
  const float* Wv     = (const float*)d_in[6];
  const float* W_ih   = (const float*)d_in[7];
  const float* W_hh   = (const float*)d_in[8];
  const float* b_ih   = (const float*)d_in[9];
  const float* b_hh   = (const float*)d_in[10];
  const float* W1     = (const float*)d_in[11];
  const float* b1     = (const float*)d_in[12];
  const float* W2     = (const float*)d_in[13];
  const float* b2     = (const float*)d_in[14];
  const float* lin_g  = (const float*)d_in[15];
  const float* lin_b  = (const float*)d_in[16];
  const float* lsl_g  = (const float*)d_in[17];
  const float* lsl_b  = (const float*)d_in[18];
  const float* lml_g  = (const float*)d_in[19];
  const float* lml_b  = (const float*)d_in[20];
  float* out = (float*)d_out;
  char* ws = (char*)d_ws;
  unsigned* x    = (unsigned*)(ws + 0);            // 134217728
  unsigned* qwb  = (unsigned*)(ws + 134217728);    // 262144
  float* stats   = (float*)(ws + 134479872);       // 32768
  float* axp     = (float*)(ws + 134610944);       // 8388608
  float* WqT     = (float*)(ws + 168165376);       // 262144
  float* WvT     = (float*)(ws + 168427520);       // 262144
  float* WihT    = (float*)(ws + 168689664);       // 786432
  float* WhhT    = (float*)(ws + 169476096);       // 786432
  float* W1T     = (float*)(ws + 170262528);       // 262144
  float* W2T     = (float*)(ws + 170524672);       // 262144

  k_pre<<<dim3(66176), 256, 0, stream>>>(inputs, lin_g, lin_b, x,
                                         Wq, Wv, W_ih, W_hh, W1, W2,
                                         WqT, WvT, WihT, WhhT, W1T, W2T);
  k_qw0<<<dim3(BATCH, 8), 256, 0, stream>>>(smu, slsig, noise, lsl_g, lsl_b,
                                            WqT, Wk, out, qwb);
  for (int it = 0; it < 3; ++it) {
    k_att4p<<<dim3(1024), 256, 0, stream>>>(x, qwb, stats, axp);
    k_update5<<<dim3(BATCH, 8), 256, 0, stream>>>(
        axp, stats, out, WvT, WihT, WhhT, b_ih, b_hh, W1T, b1, W2T, b2,
        lml_g, lml_b, lsl_g, lsl_b, WqT, Wk, qwb, (it < 2) ? 1 : 0, out);
  }
}